// Round 6
// baseline (917.813 us; speedup 1.0000x reference)
//
#include <hip/hip_runtime.h>
#include <hip/hip_bf16.h>

#define N_NODES 100000
#define N_EDGES 3200000
#define IN_DIM 128
#define HIDDEN 64
#define N_GRAPHS 512
#define SCAN_BLOCKS 391   // ceil(N_NODES/256)

typedef __hip_bfloat16 bf16;

// ---------------- CSR build ----------------
__global__ void deg_count_kernel(const int* __restrict__ dst, int* __restrict__ deg) {
    int e = blockIdx.x * blockDim.x + threadIdx.x;
    if (e < N_EDGES) atomicAdd(&deg[dst[e]], 1);
}

__global__ __launch_bounds__(256) void scan1_kernel(const int* __restrict__ cnt,
                                                    int* __restrict__ partials) {
    __shared__ int sd[256];
    int t = threadIdx.x;
    int i = blockIdx.x * 256 + t;
    sd[t] = (i < N_NODES) ? cnt[i] : 0;
    __syncthreads();
    for (int s = 128; s > 0; s >>= 1) {
        if (t < s) sd[t] += sd[t + s];
        __syncthreads();
    }
    if (t == 0) partials[blockIdx.x] = sd[0];
}

__global__ __launch_bounds__(512) void scan2_kernel(int* __restrict__ partials) {
    __shared__ int sd[512];
    int t = threadIdx.x;
    int v = (t < SCAN_BLOCKS) ? partials[t] : 0;
    sd[t] = v;
    __syncthreads();
    for (int off = 1; off < 512; off <<= 1) {
        int u = (t >= off) ? sd[t - off] : 0;
        __syncthreads();
        sd[t] += u;
        __syncthreads();
    }
    partials[t] = sd[t] - v;   // exclusive prefix
}

__global__ __launch_bounds__(256) void scan3_kernel(const int* __restrict__ cnt,
                                                    const int* __restrict__ partials,
                                                    int* __restrict__ base,
                                                    float* __restrict__ dis) {
    __shared__ int sd[256];
    int t = threadIdx.x;
    int i = blockIdx.x * 256 + t;
    int v = (i < N_NODES) ? cnt[i] : 0;
    sd[t] = v;
    __syncthreads();
    for (int off = 1; off < 256; off <<= 1) {
        int u = (t >= off) ? sd[t - off] : 0;
        __syncthreads();
        sd[t] += u;
        __syncthreads();
    }
    if (i < N_NODES) {
        base[i] = partials[blockIdx.x] + sd[t] - v;     // exclusive
        dis[i] = rsqrtf((float)(v + 1));                // +1 self-loop
    }
    if (blockIdx.x == 0 && t == 0) base[N_NODES] = N_EDGES;
}

__global__ void fill_kernel(const int* __restrict__ src, const int* __restrict__ dst,
                            const int* __restrict__ base, int* __restrict__ fcnt,
                            int* __restrict__ csr) {
    int e = blockIdx.x * blockDim.x + threadIdx.x;
    if (e < N_EDGES) {
        int d = dst[e];
        int pos = base[d] + atomicAdd(&fcnt[d], 1);
        csr[pos] = src[e];
    }
}

// ---------------- GEMM: hd[node] = bf16((in[node] @ W) * dis[node]) ----------
template <int K>
__global__ __launch_bounds__(256) void gemm_kernel(
        const float* __restrict__ in, const float* __restrict__ W,
        const float* __restrict__ dis, bf16* __restrict__ hd) {
    int tid = threadIdx.x;
    int lane = tid & 63;
    float Wr[K];
    #pragma unroll
    for (int k = 0; k < K; ++k) Wr[k] = W[k * HIDDEN + lane];   // coalesced
    int w = __builtin_amdgcn_readfirstlane(tid >> 6);           // provably uniform
    int wave = blockIdx.x * 4 + w;
    int nw = gridDim.x * 4;
    for (int n0 = wave * 4; n0 < N_NODES; n0 += nw * 4) {
        const float* xr = in + (size_t)n0 * K;
        float a0 = 0.f, a1 = 0.f, a2 = 0.f, a3 = 0.f;
        #pragma unroll
        for (int k = 0; k < K; ++k) {
            float wv = Wr[k];
            a0 = fmaf(xr[k],         wv, a0);
            a1 = fmaf(xr[K + k],     wv, a1);
            a2 = fmaf(xr[2 * K + k], wv, a2);
            a3 = fmaf(xr[3 * K + k], wv, a3);
        }
        bf16* o = hd + (size_t)n0 * HIDDEN + lane;
        o[0]          = __float2bfloat16(a0 * dis[n0]);
        o[HIDDEN]     = __float2bfloat16(a1 * dis[n0 + 1]);
        o[2 * HIDDEN] = __float2bfloat16(a2 * dis[n0 + 2]);
        o[3 * HIDDEN] = __float2bfloat16(a3 * dis[n0 + 3]);
    }
}

// ---------------- pull: 4 rows per load instruction ----------------
// Wave = four 16-lane quarters. Quarter q fetches row csr[t+q]; lane q*16+i
// loads row bytes [8i,8i+8) = channels 4i..4i+3 (packed bf16). One ds_bpermute
// distributes 4 indices per group. Cross-quarter shfl_xor butterfly at the end.
// POOL=0: act[d] = relu(row) (f32). POOL=1: atomic mean-pool of relu(row).

__device__ __forceinline__ void acc8(float4& A, uint2 u) {
    A.x += __uint_as_float(u.x << 16);
    A.y += __uint_as_float(u.x & 0xffff0000u);
    A.z += __uint_as_float(u.y << 16);
    A.w += __uint_as_float(u.y & 0xffff0000u);
}

template <int POOL>
__global__ __launch_bounds__(256) void pull_kernel(
        const bf16* __restrict__ hd, const float* __restrict__ dis,
        const int* __restrict__ base, const int* __restrict__ csr,
        const float* __restrict__ bias,
        float* __restrict__ act,
        const int* __restrict__ batch, float* __restrict__ pool,
        float* __restrict__ cnt) {
    int w = threadIdx.x >> 6, lane = threadIdx.x & 63;
    int q   = lane >> 4;     // quarter id
    int i16 = lane & 15;     // lane within quarter
    int node = blockIdx.x * 4 + w;
    if (node >= N_NODES) return;   // wave-uniform exit
    int beg = base[node], end = base[node + 1];
    const char* hdp = (const char*)hd;
    float4 A = {0.f, 0.f, 0.f, 0.f}, B = {0.f, 0.f, 0.f, 0.f};

    for (int j = beg; j < end; j += 64) {
        int rem = end - j;
        int m = rem < 64 ? rem : 64;
        int idx = (lane < m) ? csr[j + lane] : 0;
        int t = 0;
        if (m >= 8) {
            // software pipeline: keep 2 groups (8 edges) in flight
            int s0 = __builtin_amdgcn_ds_bpermute((q) * 4, idx);
            int s1 = __builtin_amdgcn_ds_bpermute((4 + q) * 4, idx);
            uint2 ua = *(const uint2*)(hdp + ((size_t)(unsigned)s0 << 7) + (i16 << 3));
            uint2 ub = *(const uint2*)(hdp + ((size_t)(unsigned)s1 << 7) + (i16 << 3));
            for (t = 8; t + 8 <= m; t += 8) {
                int n0 = __builtin_amdgcn_ds_bpermute((t + q) * 4, idx);
                int n1 = __builtin_amdgcn_ds_bpermute((t + 4 + q) * 4, idx);
                uint2 na = *(const uint2*)(hdp + ((size_t)(unsigned)n0 << 7) + (i16 << 3));
                uint2 nb = *(const uint2*)(hdp + ((size_t)(unsigned)n1 << 7) + (i16 << 3));
                acc8(A, ua); acc8(B, ub);
                ua = na; ub = nb;
            }
            acc8(A, ua); acc8(B, ub);
        }
        for (; t < m; t += 4) {   // masked tail, 4 edges at a time
            int sl = t + q;
            int s = __builtin_amdgcn_ds_bpermute((sl & 63) * 4, idx);
            uint2 u = *(const uint2*)(hdp + ((size_t)(unsigned)s << 7) + (i16 << 3));
            if (sl < m) acc8(A, u);
        }
    }
    A.x += B.x; A.y += B.y; A.z += B.z; A.w += B.w;
    // butterfly across quarters: lanes l, l^16, l^32, l^48 hold same channels
    #pragma unroll
    for (int off = 16; off < 64; off <<= 1) {
        A.x += __shfl_xor(A.x, off);
        A.y += __shfl_xor(A.y, off);
        A.z += __shfl_xor(A.z, off);
        A.w += __shfl_xor(A.w, off);
    }
    if (q == 0) {   // 16 lanes hold the full row as float4
        uint2 su = *(const uint2*)(hdp + ((size_t)node << 7) + (i16 << 3));
        float4 S = {0.f, 0.f, 0.f, 0.f};
        acc8(S, su);
        float dn = dis[node];
        float4 bb = *(const float4*)(bias + (i16 << 2));
        float4 r;
        r.x = fmaf(dn, A.x + S.x, bb.x);
        r.y = fmaf(dn, A.y + S.y, bb.y);
        r.z = fmaf(dn, A.z + S.z, bb.z);
        r.w = fmaf(dn, A.w + S.w, bb.w);
        r.x = r.x > 0.f ? r.x : 0.f;
        r.y = r.y > 0.f ? r.y : 0.f;
        r.z = r.z > 0.f ? r.z : 0.f;
        r.w = r.w > 0.f ? r.w : 0.f;
        if (POOL == 0) {
            *(float4*)(act + (size_t)node * HIDDEN + (i16 << 2)) = r;
        } else {
            int g = batch[node];
            float* pp = pool + g * HIDDEN + (i16 << 2);
            atomicAdd(pp,     r.x);
            atomicAdd(pp + 1, r.y);
            atomicAdd(pp + 2, r.z);
            atomicAdd(pp + 3, r.w);
            if (i16 == 0) atomicAdd(&cnt[g], 1.0f);
        }
    }
}

__global__ void final_kernel(const float* __restrict__ pool,
                             const float* __restrict__ cnt,
                             float* __restrict__ out) {
    int i = blockIdx.x * blockDim.x + threadIdx.x;
    if (i < N_GRAPHS * HIDDEN) {
        float c = cnt[i >> 6];
        c = c > 1.0f ? c : 1.0f;
        out[i] = pool[i] / c;
    }
}

extern "C" void kernel_launch(void* const* d_in, const int* in_sizes, int n_in,
                              void* d_out, int out_size, void* d_ws, size_t ws_size,
                              hipStream_t stream) {
    const float* x  = (const float*)d_in[0];
    const float* W1 = (const float*)d_in[1];
    const float* b1 = (const float*)d_in[2];
    const float* W2 = (const float*)d_in[3];
    const float* b2 = (const float*)d_in[4];
    const int* edge_index = (const int*)d_in[5];
    const int* batch      = (const int*)d_in[6];
    float* out = (float*)d_out;
    (void)in_sizes; (void)n_in; (void)out_size; (void)ws_size;

    char* ws = (char*)d_ws;
    int*   deg_cnt  = (int*)  (ws + 0);         // 400000
    int*   fcnt     = (int*)  (ws + 400000);    // 400000
    float* pool     = (float*)(ws + 800000);    // 131072
    float* cnt      = (float*)(ws + 931072);    // 2048
    int*   partials = (int*)  (ws + 933120);    // 2048
    float* dis      = (float*)(ws + 935168);    // 400000
    int*   base     = (int*)  (ws + 1335168);   // 400032 (padded)
    int*   csr      = (int*)  (ws + 1735200);   // 12800000
    bf16*  hd       = (bf16*) (ws + 14535200);  // 12800000
    float* act      = (float*)(ws + 27335200);  // 25600000 -> ends 52935200

    const int* srcv = edge_index;            // edge_index[0]
    const int* dstv = edge_index + N_EDGES;  // edge_index[1]

    // zero: deg_cnt, fcnt, pool, cnt (contiguous region)
    hipMemsetAsync(ws, 0, 933120, stream);

    // CSR build (reused by both layers)
    deg_count_kernel<<<(N_EDGES + 255) / 256, 256, 0, stream>>>(dstv, deg_cnt);
    scan1_kernel<<<SCAN_BLOCKS, 256, 0, stream>>>(deg_cnt, partials);
    scan2_kernel<<<1, 512, 0, stream>>>(partials);
    scan3_kernel<<<SCAN_BLOCKS, 256, 0, stream>>>(deg_cnt, partials, base, dis);
    fill_kernel<<<(N_EDGES + 255) / 256, 256, 0, stream>>>(srcv, dstv, base, fcnt, csr);

    // layer 1: hd = bf16((x@W1)*dis) ; act = relu(dis*(gather+self) + b1)
    gemm_kernel<IN_DIM><<<1024, 256, 0, stream>>>(x, W1, dis, hd);
    pull_kernel<0><<<(N_NODES + 3) / 4, 256, 0, stream>>>(hd, dis, base, csr, b1,
                                                          act, nullptr, nullptr, nullptr);

    // layer 2: hd = bf16((act@W2)*dis) ; fused relu+b2+mean-pool atomics
    gemm_kernel<HIDDEN><<<1024, 256, 0, stream>>>(act, W2, dis, hd);
    pull_kernel<1><<<(N_NODES + 3) / 4, 256, 0, stream>>>(hd, dis, base, csr, b2,
                                                          nullptr, batch, pool, cnt);

    final_kernel<<<(N_GRAPHS * HIDDEN + 255) / 256, 256, 0, stream>>>(pool, cnt, out);
}